// Round 3
// baseline (4377.682 us; speedup 1.0000x reference)
//
#include <hip/hip_runtime.h>
#include <hip/hip_bf16.h>

#define B_ 256
#define T_ 128
#define D_ 512
#define H_ 1024
#define FC_ 1024
#define A_ 32

typedef short bf16x8 __attribute__((ext_vector_type(8)));
typedef float f32x4 __attribute__((ext_vector_type(4)));

__device__ __forceinline__ float bf2f(unsigned short u) {
  return __uint_as_float(((unsigned)u) << 16);
}
// round-to-nearest-even fp32 -> bf16
__device__ __forceinline__ unsigned short f2bf(float x) {
  unsigned u = __float_as_uint(x);
  u = u + 0x7fffu + ((u >> 16) & 1u);
  return (unsigned short)(u >> 16);
}
__device__ __forceinline__ void unpack8(uint4 v, float* f) {
  f[0] = bf2f(v.x & 0xffff); f[1] = bf2f(v.x >> 16);
  f[2] = bf2f(v.y & 0xffff); f[3] = bf2f(v.y >> 16);
  f[4] = bf2f(v.z & 0xffff); f[5] = bf2f(v.z >> 16);
  f[6] = bf2f(v.w & 0xffff); f[7] = bf2f(v.w >> 16);
}
__device__ __forceinline__ uint4 pack8(const float* f) {
  uint4 v;
  v.x = (unsigned)f2bf(f[0]) | ((unsigned)f2bf(f[1]) << 16);
  v.y = (unsigned)f2bf(f[2]) | ((unsigned)f2bf(f[3]) << 16);
  v.z = (unsigned)f2bf(f[4]) | ((unsigned)f2bf(f[5]) << 16);
  v.w = (unsigned)f2bf(f[6]) | ((unsigned)f2bf(f[7]) << 16);
  return v;
}

// ------------- dtype probe: bf16 inputs -> flag 0, fp32 inputs -> flag 1 -----
// fp32 reinterpreted as bf16 halves gives random exponents (~48% >= 0x86);
// genuine bf16 N(0,1) never exceeds |v|=64. Count over 8192 half-words.
__global__ __launch_bounds__(256) void detect_kernel(
    const unsigned short* __restrict__ obs, int* __restrict__ flag)
{
  __shared__ int cnt;
  if (threadIdx.x == 0) cnt = 0;
  __syncthreads();
  int c = 0;
  for (int i = threadIdx.x; i < 8192; i += 256) {
    unsigned e = (obs[i] >> 7) & 0xffu;  // bf16 exponent field
    if (e >= 0x86u) c++;
  }
  atomicAdd(&cnt, c);
  __syncthreads();
  if (threadIdx.x == 0) *flag = (cnt >= 64) ? 1 : 0;
}

// ------------- canonicalize 14 float tensors to bf16 workspace copies -------
struct CanonArgs {
  const void* src[14];
  unsigned short* dst[14];
  int ofs[15];  // cumulative element offsets (all multiples of 8)
};
__global__ __launch_bounds__(256) void canon_kernel(CanonArgs a,
                                                    const int* __restrict__ flag)
{
  const int fl = *flag;
  const int i0 = (blockIdx.x * 256 + threadIdx.x) * 8;
  int t = 0;
  while (t < 14 && i0 >= a.ofs[t + 1]) t++;
  if (t >= 14) return;
  const int local = i0 - a.ofs[t];
  unsigned short* d = a.dst[t] + local;
  if (fl) {
    const float* s = (const float*)a.src[t] + local;
    #pragma unroll
    for (int e = 0; e < 8; e++) d[e] = f2bf(s[e]);
  } else {
    const unsigned short* s = (const unsigned short*)a.src[t] + local;
    #pragma unroll
    for (int e = 0; e < 8; e++) d[e] = s[e];
  }
}

// ---------------- LayerNorm: one wave per row of D=512 (chunked over t) ------
__global__ __launch_bounds__(256) void ln_kernel(
    const void* __restrict__ obs,
    const unsigned short* __restrict__ gamma_,
    const unsigned short* __restrict__ beta_,
    unsigned short* __restrict__ xn, int t0, int tcShift,
    const int* __restrict__ flag)
{
  const int fl = *flag;
  const int lane = threadIdx.x & 63;
  const int rloc = blockIdx.x * 4 + (threadIdx.x >> 6);
  const int b  = rloc >> tcShift;
  const int tl = rloc & ((1 << tcShift) - 1);
  const int grow = b * T_ + t0 + tl;
  float f[8];
  if (fl) {
    const float* of = (const float*)obs + (size_t)grow * D_ + lane * 8;
    const float4 v0 = *(const float4*)of;
    const float4 v1 = *(const float4*)(of + 4);
    f[0] = v0.x; f[1] = v0.y; f[2] = v0.z; f[3] = v0.w;
    f[4] = v1.x; f[5] = v1.y; f[6] = v1.z; f[7] = v1.w;
  } else {
    uint4 v = *(const uint4*)((const unsigned short*)obs + (size_t)grow * D_ + lane * 8);
    unpack8(v, f);
  }
  float s = 0.f, ss = 0.f;
  #pragma unroll
  for (int i = 0; i < 8; i++) { s += f[i]; ss += f[i] * f[i]; }
  #pragma unroll
  for (int off = 32; off > 0; off >>= 1) {
    s  += __shfl_xor(s,  off, 64);
    ss += __shfl_xor(ss, off, 64);
  }
  const float mu  = s * (1.0f / D_);
  const float var = ss * (1.0f / D_) - mu * mu;
  const float inv = rsqrtf(var + 1e-5f);
  float g[8], b8[8];
  unpack8(*(const uint4*)(gamma_ + lane * 8), g);
  unpack8(*(const uint4*)(beta_  + lane * 8), b8);
  float o[8];
  #pragma unroll
  for (int i = 0; i < 8; i++) o[i] = (f[i] - mu) * inv * g[i] + b8[i];
  *(uint4*)(xn + (size_t)rloc * D_ + lane * 8) = pack8(o);
}

// ------------- generic TN GEMM: C[M,N] = A[M,K] * B[N,K]^T + bias -------------
__global__ __launch_bounds__(256) void gemm_tn(
    const unsigned short* __restrict__ A, const unsigned short* __restrict__ Bm,
    const unsigned short* __restrict__ bias, unsigned short* __restrict__ C,
    int M, int N, int K, int relu)
{
  __shared__ short As[128][40];
  __shared__ short Bs[128][40];
  const int tid  = threadIdx.x;
  const int wave = tid >> 6, lane = tid & 63;
  const int quad = lane >> 4, l15 = lane & 15;
  const int m0 = blockIdx.y * 128, n0 = blockIdx.x * 128;
  const int wm = (wave >> 1) * 64, wn = (wave & 1) * 64;
  const int lrow = tid >> 2, lk = (tid & 3) * 8;
  f32x4 acc[4][4] = {};
  const size_t a0 = (size_t)(m0 + lrow) * K + lk;
  const size_t a1 = (size_t)(m0 + lrow + 64) * K + lk;
  const size_t b0 = (size_t)(n0 + lrow) * K + lk;
  const size_t b1 = (size_t)(n0 + lrow + 64) * K + lk;
  for (int k0 = 0; k0 < K; k0 += 32) {
    __syncthreads();
    *(uint4*)&As[lrow][lk]      = *(const uint4*)(A  + a0 + k0);
    *(uint4*)&As[lrow + 64][lk] = *(const uint4*)(A  + a1 + k0);
    *(uint4*)&Bs[lrow][lk]      = *(const uint4*)(Bm + b0 + k0);
    *(uint4*)&Bs[lrow + 64][lk] = *(const uint4*)(Bm + b1 + k0);
    __syncthreads();
    bf16x8 af[4], bfv[4];
    #pragma unroll
    for (int i = 0; i < 4; i++) af[i]  = *(const bf16x8*)&As[wm + i * 16 + l15][quad * 8];
    #pragma unroll
    for (int j = 0; j < 4; j++) bfv[j] = *(const bf16x8*)&Bs[wn + j * 16 + l15][quad * 8];
    #pragma unroll
    for (int i = 0; i < 4; i++)
      #pragma unroll
      for (int j = 0; j < 4; j++)
        acc[i][j] = __builtin_amdgcn_mfma_f32_16x16x32_bf16(af[i], bfv[j], acc[i][j], 0, 0, 0);
  }
  #pragma unroll
  for (int j = 0; j < 4; j++) {
    const int col = n0 + wn + j * 16 + l15;
    const float bj = bias ? bf2f(bias[col]) : 0.0f;
    #pragma unroll
    for (int i = 0; i < 4; i++) {
      const int row = m0 + wm + i * 16 + quad * 4;
      #pragma unroll
      for (int r = 0; r < 4; r++) {
        float v = acc[i][j][r] + bj;
        if (relu) v = fmaxf(v, 0.0f);
        C[(size_t)(row + r) * N + col] = f2bf(v);
      }
    }
  }
}

// ------------- GRU step: gh = (mask.h) W_hh^T, gate, write h_new -------------
__global__ __launch_bounds__(256) void gru_step(
    const float* __restrict__ h_in, float* __restrict__ h_out,
    const unsigned short* __restrict__ xg, const int* __restrict__ starts,
    const unsigned short* __restrict__ Whh, const unsigned short* __restrict__ bhh,
    unsigned short* __restrict__ h_all, int t, int tl, int Tc)
{
  __shared__ short Hs[32][40];
  __shared__ short Ws[3][64][40];
  const int tid  = threadIdx.x;
  const int wave = tid >> 6, lane = tid & 63;
  const int quad = lane >> 4, l15 = lane & 15;
  const int b0 = blockIdx.y * 32, j0 = blockIdx.x * 64;
  const int wm = (wave >> 1) * 16, wn = (wave & 1) * 32;
  const int lrow = tid >> 2, lk = (tid & 3) * 8;
  f32x4 acc[3][2] = {};
  float keep = 0.0f;
  if (lrow < 32) keep = starts[(b0 + lrow) * T_ + t] ? 0.0f : 1.0f;
  for (int k0 = 0; k0 < H_; k0 += 32) {
    __syncthreads();
    if (lrow < 32) {
      const float* hp = h_in + (size_t)(b0 + lrow) * H_ + k0 + lk;
      float f[8];
      #pragma unroll
      for (int e = 0; e < 8; e++) f[e] = hp[e] * keep;
      *(uint4*)&Hs[lrow][lk] = pack8(f);
    }
    #pragma unroll
    for (int g = 0; g < 3; g++)
      *(uint4*)&Ws[g][lrow][lk] =
          *(const uint4*)(Whh + (size_t)(g * H_ + j0 + lrow) * H_ + k0 + lk);
    __syncthreads();
    bf16x8 af = *(const bf16x8*)&Hs[wm + l15][quad * 8];
    #pragma unroll
    for (int g = 0; g < 3; g++)
      #pragma unroll
      for (int j = 0; j < 2; j++) {
        bf16x8 bfv = *(const bf16x8*)&Ws[g][wn + j * 16 + l15][quad * 8];
        acc[g][j] = __builtin_amdgcn_mfma_f32_16x16x32_bf16(af, bfv, acc[g][j], 0, 0, 0);
      }
  }
  #pragma unroll
  for (int r = 0; r < 4; r++) {
    const int b = b0 + wm + quad * 4 + r;
    const float kb = starts[b * T_ + t] ? 0.0f : 1.0f;
    const size_t xrow = ((size_t)b * Tc + tl) * (3 * H_);
    #pragma unroll
    for (int j = 0; j < 2; j++) {
      const int col = j0 + wn + j * 16 + l15;
      const float hr = acc[0][j][r] + bf2f(bhh[col]);
      const float hz = acc[1][j][r] + bf2f(bhh[H_ + col]);
      const float hn = acc[2][j][r] + bf2f(bhh[2 * H_ + col]);
      const float xr  = bf2f(xg[xrow + col]);
      const float xz  = bf2f(xg[xrow + H_ + col]);
      const float xnv = bf2f(xg[xrow + 2 * H_ + col]);
      const float rg = 1.0f / (1.0f + __expf(-(xr + hr)));
      const float zg = 1.0f / (1.0f + __expf(-(xz + hz)));
      const float ng = tanhf(xnv + rg * hn);
      const float hm = h_in[(size_t)b * H_ + col] * kb;
      const float hv = (1.0f - zg) * ng + zg * hm;
      h_out[(size_t)b * H_ + col] = hv;
      h_all[((size_t)b * Tc + tl) * H_ + col] = f2bf(hv);
    }
  }
}

// ------------- heads: means & log_std fused (N=64), dual-dtype store ---------
__global__ __launch_bounds__(256) void heads_kernel(
    const unsigned short* __restrict__ feats,
    const unsigned short* __restrict__ Wm, const unsigned short* __restrict__ bm,
    const unsigned short* __restrict__ Wl, const unsigned short* __restrict__ bl,
    void* __restrict__ outbuf, int t0, int tcShift, const int* __restrict__ flag)
{
  __shared__ short Fs[64][40];
  __shared__ short Ws[64][40];
  const int fl = *flag;
  const int tid  = threadIdx.x;
  const int wave = tid >> 6, lane = tid & 63;
  const int quad = lane >> 4, l15 = lane & 15;
  const int m0 = blockIdx.x * 64;
  const int lrow = tid >> 2, lk = (tid & 3) * 8;
  f32x4 acc[4] = {};
  for (int k0 = 0; k0 < H_; k0 += 32) {
    __syncthreads();
    *(uint4*)&Fs[lrow][lk] = *(const uint4*)(feats + (size_t)(m0 + lrow) * H_ + k0 + lk);
    const unsigned short* wsrc = (lrow < 32)
        ? (Wm + (size_t)lrow * H_ + k0 + lk)
        : (Wl + (size_t)(lrow - 32) * H_ + k0 + lk);
    *(uint4*)&Ws[lrow][lk] = *(const uint4*)wsrc;
    __syncthreads();
    bf16x8 af = *(const bf16x8*)&Fs[wave * 16 + l15][quad * 8];
    #pragma unroll
    for (int j = 0; j < 4; j++) {
      bf16x8 bfv = *(const bf16x8*)&Ws[j * 16 + l15][quad * 8];
      acc[j] = __builtin_amdgcn_mfma_f32_16x16x32_bf16(af, bfv, acc[j], 0, 0, 0);
    }
  }
  const int tcMask = (1 << tcShift) - 1;
  const size_t lstdBase = (size_t)B_ * T_ * A_;
  #pragma unroll
  for (int j = 0; j < 4; j++) {
    const int col = j * 16 + l15;
    #pragma unroll
    for (int r = 0; r < 4; r++) {
      const int row = m0 + wave * 16 + quad * 4 + r;  // chunk-local
      const int grow = (row >> tcShift) * T_ + t0 + (row & tcMask);
      float v = acc[j][r];
      size_t idx;
      if (col < 32) {
        v += bf2f(bm[col]);
        idx = (size_t)grow * A_ + col;
      } else {
        v += bf2f(bl[col - 32]);
        v = fminf(fmaxf(v, -20.0f), 2.0f);
        idx = lstdBase + (size_t)grow * A_ + (col - 32);
      }
      if (fl) ((float*)outbuf)[idx] = v;
      else    ((unsigned short*)outbuf)[idx] = f2bf(v);
    }
  }
}

__global__ __launch_bounds__(256) void h0_cast(const void* __restrict__ h0,
                                               float* __restrict__ out,
                                               const int* __restrict__ flag) {
  const int fl = *flag;
  int i = blockIdx.x * 256 + threadIdx.x;
  out[i] = fl ? ((const float*)h0)[i] : bf2f(((const unsigned short*)h0)[i]);
}
__global__ __launch_bounds__(256) void hfin_store(const float* __restrict__ h,
                                                  void* __restrict__ outbuf,
                                                  const int* __restrict__ flag) {
  const int fl = *flag;
  const size_t base = 2ull * B_ * T_ * A_;
  int i = blockIdx.x * 256 + threadIdx.x;
  if (fl) ((float*)outbuf)[base + i] = h[i];
  else    ((unsigned short*)outbuf)[base + i] = f2bf(h[i]);
}

extern "C" void kernel_launch(void* const* d_in, const int* in_sizes, int n_in,
                              void* d_out, int out_size, void* d_ws, size_t ws_size,
                              hipStream_t stream)
{
  const void* obs    = d_in[0];
  const void* h0in   = d_in[1];
  const int*  starts = (const int*)d_in[2];
  // float tensors to canonicalize (order matters for CanonArgs):
  const void* fsrc[14] = { d_in[5], d_in[7], d_in[9], d_in[11], d_in[13], d_in[15],
                           d_in[3], d_in[4], d_in[6], d_in[8], d_in[10], d_in[12],
                           d_in[14], d_in[16] };
  const int fn[14] = { FC_ * D_, 3 * H_ * FC_, 3 * H_ * H_, H_ * H_, A_ * H_, A_ * H_,
                       D_, D_, FC_, 3 * H_, 3 * H_, H_, A_, A_ };

  char* ws = (char*)d_ws;
  int* flag = (int*)ws;
  size_t cur = 256;
  unsigned short* cdst[14];
  for (int i = 0; i < 14; i++) {
    cdst[i] = (unsigned short*)(ws + cur);
    cur += (size_t)fn[i] * 2;
    cur = (cur + 255) & ~255ull;  // keep 16B alignment generously
  }
  const size_t chunkBase = cur;

  // Pick largest Tc with: chunkBase + Tc*2883584 + 2*B*H*4 <= ws_size
  int Tc = 1;
  for (int c = 32; c >= 1; c >>= 1) {
    size_t need = chunkBase + (size_t)c * 2883584ull + 2ull * B_ * H_ * 4ull;
    if (need <= ws_size) { Tc = c; break; }
  }
  int tcShift = 0;
  while ((1 << tcShift) < Tc) tcShift++;

  unsigned short* xn   = (unsigned short*)(ws + chunkBase);
  unsigned short* xfc  = (unsigned short*)(ws + chunkBase + (size_t)Tc * 262144ull);
  unsigned short* xg   = (unsigned short*)(ws + chunkBase + (size_t)Tc * 786432ull);
  unsigned short* hall = (unsigned short*)(ws + chunkBase + (size_t)Tc * 2359296ull);
  float* hbuf0         = (float*)(ws + chunkBase + (size_t)Tc * 2883584ull);
  float* hbuf1         = hbuf0 + (size_t)B_ * H_;
  unsigned short* feats = xg;  // xg dead once the chunk's scan is done

  const unsigned short *Wfc = cdst[0], *Wih = cdst[1], *Whh = cdst[2], *Wout = cdst[3];
  const unsigned short *Wmean = cdst[4], *Wls = cdst[5];
  const unsigned short *gam = cdst[6], *bet = cdst[7], *bfc = cdst[8], *bih = cdst[9];
  const unsigned short *bhh = cdst[10], *bout = cdst[11], *bmean = cdst[12], *bls = cdst[13];

  // dtype probe + canonicalization
  detect_kernel<<<dim3(1), dim3(256), 0, stream>>>((const unsigned short*)obs, flag);
  CanonArgs ca;
  int total = 0;
  for (int i = 0; i < 14; i++) {
    ca.src[i] = fsrc[i];
    ca.dst[i] = cdst[i];
    ca.ofs[i] = total;
    total += fn[i];
  }
  ca.ofs[14] = total;
  canon_kernel<<<dim3((total / 8 + 255) / 256), dim3(256), 0, stream>>>(ca, flag);
  h0_cast<<<dim3(B_ * H_ / 256), dim3(256), 0, stream>>>(h0in, hbuf0, flag);

  const int Mc = B_ * Tc;  // chunk GEMM rows (256*Tc, multiple of 128)
  for (int t0 = 0; t0 < T_; t0 += Tc) {
    ln_kernel<<<dim3(Mc / 4), dim3(256), 0, stream>>>(obs, gam, bet, xn, t0, tcShift, flag);
    gemm_tn<<<dim3(FC_ / 128, Mc / 128), dim3(256), 0, stream>>>(
        xn, Wfc, bfc, xfc, Mc, FC_, D_, 1);
    gemm_tn<<<dim3(3 * H_ / 128, Mc / 128), dim3(256), 0, stream>>>(
        xfc, Wih, bih, xg, Mc, 3 * H_, FC_, 0);

    for (int tl = 0; tl < Tc; tl++) {
      const int t = t0 + tl;
      const float* hi = (t & 1) ? hbuf1 : hbuf0;
      float*       ho = (t & 1) ? hbuf0 : hbuf1;
      gru_step<<<dim3(H_ / 64, B_ / 32), dim3(256), 0, stream>>>(
          hi, ho, xg, starts, Whh, bhh, hall, t, tl, Tc);
    }

    gemm_tn<<<dim3(H_ / 128, Mc / 128), dim3(256), 0, stream>>>(
        hall, Wout, bout, feats, Mc, H_, H_, 1);
    heads_kernel<<<dim3(Mc / 64), dim3(256), 0, stream>>>(
        feats, Wmean, bmean, Wls, bls, d_out, t0, tcShift, flag);
  }

  // T_=128 even -> final h is in hbuf0
  hfin_store<<<dim3(B_ * H_ / 256), dim3(256), 0, stream>>>(hbuf0, d_out, flag);
}